// Round 17
// baseline (415.073 us; speedup 1.0000x reference)
//
#include <hip/hip_runtime.h>
#include <cstdint>
#include <cstddef>

#define TAU_D 2.053748910631823
#define M_DIM 8192
#define N_DIM 4096
#define K_DIM 4096
#define NT32  (K_DIM / 32)     // 128 K-steps of BK=32

typedef float f32x4  __attribute__((ext_vector_type(4)));
typedef short bf16x8 __attribute__((ext_vector_type(8)));

typedef __attribute__((address_space(1))) void gvoid_t;
typedef __attribute__((address_space(3))) void lvoid_t;

__device__ __forceinline__ void gload_lds16(const void* g, void* l) {
    __builtin_amdgcn_global_load_lds((const gvoid_t*)g, (lvoid_t*)l, 16, 0, 0);
}

__device__ __forceinline__ unsigned int pack2bf(float lo, float hi) {
    unsigned int ul = __float_as_uint(lo);
    unsigned int uh = __float_as_uint(hi);
    ul = (ul + 0x7FFFu + ((ul >> 16) & 1u)) >> 16;
    uh = (uh + 0x7FFFu + ((uh >> 16) & 1u)) >> 16;
    return ul | (uh << 16);
}

// fp32 -> bf16 (RNE), vectorized: 16B in / 8B out per thread per iter.
__global__ void cvt_f32_to_bf16(const float4* __restrict__ in,
                                uint2* __restrict__ out, int n4) {
    int i = blockIdx.x * blockDim.x + threadIdx.x;
    const int stride = gridDim.x * blockDim.x;
    for (; i < n4; i += stride) {
        float4 a = in[i];
        uint2 o;
        o.x = pack2bf(a.x, a.y);
        o.y = pack2bf(a.z, a.w);
        out[i] = o;
    }
}

// Raw barrier + compiler-only memory fence.
#define BAR() do { __builtin_amdgcn_s_barrier(); \
                   asm volatile("" ::: "memory"); } while (0)

// ============================================================================
// 2-BLOCKS/CU CROSS-BLOCK MULTIPLEXING (m114 mechanism). 11 intra-block
// schedule variants plateaued at MfmaUtil 47% -- the sync bubbles need ANOTHER
// block's waves to fill them. r8 failed at 2 blocks/CU because the 256x256
// tile needs 128 acc VGPR; this kernel shrinks the tile instead:
//   256x128 tile, 8 waves (4M x 2N), per-wave 64x64 -> acc = 64 VGPR,
//   BK=32 (1 MFMA per frag pair): aF[4]+bF[4] = 32 VGPR; total ~120 <= 128
//   -> __launch_bounds__(512,4) = 2 blocks/CU (LDS 72KB/block, 144<=160).
// Per K-step span (ONE barrier): [reads A4+B4 | stage(T+2)->buf[(T+2)%3] |
// 16 MFMA (setprio) | vmcnt(3) | BAR]. The co-resident block covers the
// read-latency and vmcnt/barrier bubbles.
// Ledger: prologue stages K0,K1, vmcnt(3) -> K0 landed. Span T: outstanding
// at vmcnt = [T+1's 3][T+2's 3]; vmcnt(3) forces T+1 (read next span), 3 fly.
// Tail: T=NT-2 vmcnt(0); T=NT-1 none. WAR: buf[(T+2)%3] last read span T-1,
// one barrier + >=400cy gload-write latency apart (validated r7/r14-r16).
// Swizzle (r7-verified, BK=32): phys 16B-slot = (logical + (row>>1)) & 3;
// staging pre-rotates the GLOBAL source column; LDS dest linear.
// XCD map: 1024 blocks; per XCD per round an 8x8 tile cluster (bijective).
// Epilogue: bit-exact fp32 sgemm-replica mask (verified r3-r16), n-paired
// line-complete stores.
// ============================================================================
__global__ __launch_bounds__(512, 4) void gemm_masked8(
    const unsigned short* __restrict__ Ab,   // x bf16 [M][K]
    const unsigned short* __restrict__ Bb,   // W bf16 [N][K]
    const float* __restrict__ X,             // x fp32 (mask)
    const float* __restrict__ Wt,            // W fp32 (mask)
    const float* __restrict__ bias,
    float* __restrict__ out)
{
    __shared__ __align__(16) char lds[73728];   // 3 x (A 16KB + B 8KB)

    const int tid  = threadIdx.x;
    const int wave = tid >> 6;
    const int lane = tid & 63;
    const int lr = lane & 15;
    const int lq = lane >> 4;
    const int wm = wave >> 1;    // 0..3 : 64-row slice
    const int wn = wave & 1;     // 0..1 : 64-col slice

    // XCD cluster map: 1024 blocks, 2 blocks/CU -> 512 concurrent (round 0).
    // xcd = flat&7; per XCD per round: 8 tile-rows x 8 tile-cols. Bijective.
    const int flat = blockIdx.x;
    const int xcd  = flat & 7;
    const int s    = flat >> 3;            // 0..127
    const int rnd  = s >> 6;               // 0..1
    const int jj   = s & 63;               // 0..63
    const int trow = rnd * 16 + ((xcd >> 2) << 3) + (jj >> 3);   // 0..31
    const int tcol = ((xcd & 3) << 3) + (jj & 7);                // 0..31
    const int rowBase = trow * 256;
    const int colBase = tcol * 128;

    f32x4 acc[4][4];
    #pragma unroll
    for (int i = 0; i < 4; ++i)
        #pragma unroll
        for (int n = 0; n < 4; ++n)
            acc[i][n] = (f32x4){0.f, 0.f, 0.f, 0.f};

    // ---- staging (r7-verified swizzle): linear LDS dest; src col rotated --
    // A pass i (i=0,1): row = i*128 + (tid>>2), phys slot = tid&3.
    // B single pass:    row = tid>>2 (0..127),  phys slot = tid&3.
    // logical slot = ((tid&3) - ((tid>>3)&3)) & 3  (phys = (log+(row>>1))&3).
    const int srow = tid >> 2;                                   // 0..127
    const int slog = ((tid & 3) - ((tid >> 3) & 3)) & 3;
    const unsigned short* aSrc =
        Ab + (size_t)(rowBase + srow) * K_DIM + slog * 8;
    const unsigned short* bSrc =
        Bb + (size_t)(colBase + srow) * K_DIM + slog * 8;

    auto stageK = [&](int kst, unsigned bo) {   // 3 gloads: A x2 + B x1
        #pragma unroll
        for (int i = 0; i < 2; ++i)
            gload_lds16(aSrc + (size_t)i * 128 * K_DIM + kst * 32,
                        lds + bo + i * 8192 + wave * 1024);
        gload_lds16(bSrc + kst * 32, lds + bo + 16384 + wave * 1024);
    };

    // ---- ds_read offsets: byte = row*64 + ((lq + (lr>>1)) & 3)*16 ----
    const unsigned rot  = (unsigned)((lq + (lr >> 1)) & 3) * 16;
    const unsigned offA = (unsigned)(wm * 64 + lr) * 64 + rot;          // +m*1024
    const unsigned offB = 16384u + (unsigned)(wn * 64 + lr) * 64 + rot; // +n*1024

    // ---- prologue: stage K0,K1; vmcnt(3) (K0 landed, K1 flying); BAR ----
    stageK(0, 0);
    stageK(1, 24576);
    asm volatile("s_waitcnt vmcnt(3)" ::: "memory");
    BAR();

    unsigned b0 = 0, b1 = 24576, b2 = 49152;   // read T / T+1 / stage T+2

    for (int T = 0; T < NT32; ++T) {
        const char* L = lds + b0;

        bf16x8 aF[4], bF[4];
        #pragma unroll
        for (int m = 0; m < 4; ++m)
            aF[m] = *(const bf16x8*)(L + offA + m * 1024);
        #pragma unroll
        for (int n = 0; n < 4; ++n)
            bF[n] = *(const bf16x8*)(L + offB + n * 1024);
        if (T + 2 < NT32) stageK(T + 2, b2);

        __builtin_amdgcn_s_setprio(1);
        #pragma unroll
        for (int m = 0; m < 4; ++m)
            #pragma unroll
            for (int n = 0; n < 4; ++n)
                acc[m][n] = __builtin_amdgcn_mfma_f32_16x16x32_bf16(
                    aF[m], bF[n], acc[m][n], 0, 0, 0);
        __builtin_amdgcn_s_setprio(0);

        if (T + 2 < NT32) {
            asm volatile("s_waitcnt vmcnt(3)" ::: "memory");  // T+1 landed
        } else if (T + 1 < NT32) {
            asm volatile("s_waitcnt vmcnt(0)" ::: "memory");  // tail drain
        }
        BAR();

        unsigned t = b0; b0 = b1; b1 = b2; b2 = t;
    }

    // ---- epilogue: bit-exact fp32 mask + bias + store (verified r3-r16) ---
    __syncthreads();
    float* x0s = (float*)(lds);            // [256][16] f32, 16KB
    float* w0s = (float*)(lds + 16384);    // [128][16] f32, 8KB
    #pragma unroll
    for (int i = 0; i < 2; ++i) {
        int idx = tid + i * 512;           // 1024 float4 slots
        int r = idx >> 2, qq = (idx & 3) << 2;
        *(f32x4*)(x0s + r * 16 + qq) =
            *(const f32x4*)(X + (size_t)(rowBase + r) * K_DIM + qq);
    }
    {
        int r = tid >> 2, qq = (tid & 3) << 2;   // 512 float4 slots
        *(f32x4*)(w0s + r * 16 + qq) =
            *(const f32x4*)(Wt + (size_t)(colBase + r) * K_DIM + qq);
    }
    __syncthreads();

    const float TAU32 = (float)TAU_D;

    // n in adjacent pairs: both 64B halves of each 128B output line stored
    // back-to-back (write-amplification fix, verified r6-r16).
    #pragma unroll
    for (int np = 0; np < 4; np += 2) {
        float wv[2][16];
        float bv[2];
        #pragma unroll
        for (int e = 0; e < 2; ++e) {
            const int c = wn * 64 + (np + e) * 16 + lr;
            #pragma unroll
            for (int q = 0; q < 4; ++q)
                *(f32x4*)&wv[e][q * 4] = *(const f32x4*)(w0s + c * 16 + q * 4);
            bv[e] = bias[colBase + c];
        }
        #pragma unroll
        for (int mi = 0; mi < 4; ++mi) {
            #pragma unroll
            for (int jr = 0; jr < 4; ++jr) {
                const int rw = wm * 64 + mi * 16 + lq * 4 + jr;
                float xv[16];
                #pragma unroll
                for (int q = 0; q < 4; ++q)
                    *(f32x4*)&xv[q * 4] = *(const f32x4*)(x0s + rw * 16 + q * 4);
                const size_t orow = (size_t)(rowBase + rw) * N_DIM + colBase;
                #pragma unroll
                for (int e = 0; e < 2; ++e) {
                    const int n = np + e;
                    // Replicate BLAS sgemm: single-acc fma chain, k ascending.
                    float y1 = 0.f, s2 = 0.f;
                    #pragma unroll
                    for (int k = 0; k < 16; ++k) {
                        float xk = xv[k], wk = wv[e][k];
                        float xx = xk * xk, ww = wk * wk;
                        y1 = fmaf(xk, wk, y1);
                        s2 = fmaf(xx, ww, s2);
                    }
                    float t = fabsf(y1) / sqrtf(s2 * 0.0625f);
                    float v = (t < TAU32) ? 0.0f : (acc[mi][n][jr] + bv[e]);
                    out[orow + wn * 64 + n * 16 + lr] = v;
                }
            }
        }
    }
}

// ============================================================================
// Fallback (no workspace): round-3 verified 128x128 kernel, reg-staged cvt.
// ============================================================================
__global__ __launch_bounds__(256, 2) void gemm_masked_fb(
    const float* __restrict__ X, const float* __restrict__ Wt,
    const float* __restrict__ bias, float* __restrict__ out)
{
    __shared__ __align__(16) unsigned short As[128 * 32];
    __shared__ __align__(16) unsigned short Bs[128 * 32];

    const int tid  = threadIdx.x;
    const int wave = tid >> 6;
    const int lane = tid & 63;
    const int rowBase = blockIdx.y * 128;
    const int colBase = blockIdx.x * 128;
    const int wr = wave >> 1;
    const int wc = wave & 1;
    const int lr = lane & 15;
    const int lq = lane >> 4;

    f32x4 acc[4][4];
    #pragma unroll
    for (int m = 0; m < 4; ++m)
        #pragma unroll
        for (int n = 0; n < 4; ++n)
            acc[m][n] = (f32x4){0.f, 0.f, 0.f, 0.f};

    const int srow = tid >> 2;
    const int scol = (tid & 3) * 8;
    const float* afp = X  + (size_t)(rowBase + srow) * K_DIM + scol;
    const float* bfp = Wt + (size_t)(colBase + srow) * K_DIM + scol;

    for (int kt = 0; kt < K_DIM; kt += 32) {
        #pragma unroll
        for (int issue = 0; issue < 2; ++issue) {
            const float* sa = afp + (size_t)issue * 64 * K_DIM;
            const float* sb = bfp + (size_t)issue * 64 * K_DIM;
            float4 a0 = *(const float4*)(sa);
            float4 a1 = *(const float4*)(sa + 4);
            float4 b0 = *(const float4*)(sb);
            float4 b1 = *(const float4*)(sb + 4);
            uint4 pa, pb;
            pa.x = pack2bf(a0.x, a0.y); pa.y = pack2bf(a0.z, a0.w);
            pa.z = pack2bf(a1.x, a1.y); pa.w = pack2bf(a1.z, a1.w);
            pb.x = pack2bf(b0.x, b0.y); pb.y = pack2bf(b0.z, b0.w);
            pb.z = pack2bf(b1.x, b1.y); pb.w = pack2bf(b1.z, b1.w);
            *(uint4*)((char*)As + issue * 4096 + tid * 16) = pa;
            *(uint4*)((char*)Bs + issue * 4096 + tid * 16) = pb;
        }
        afp += 32; bfp += 32;
        __syncthreads();

        bf16x8 af[4], bq[4];
        #pragma unroll
        for (int m = 0; m < 4; ++m)
            af[m] = *(const bf16x8*)(As + (wr * 64 + m * 16 + lr) * 32 + lq * 8);
        #pragma unroll
        for (int n = 0; n < 4; ++n)
            bq[n] = *(const bf16x8*)(Bs + (wc * 64 + n * 16 + lr) * 32 + lq * 8);
        #pragma unroll
        for (int m = 0; m < 4; ++m)
            #pragma unroll
            for (int n = 0; n < 4; ++n)
                acc[m][n] = __builtin_amdgcn_mfma_f32_16x16x32_bf16(
                    af[m], bq[n], acc[m][n], 0, 0, 0);
        __syncthreads();
    }

    float* x0s = (float*)As;
    float* w0s = (float*)Bs;
    #pragma unroll
    for (int i = 0; i < 2; ++i) {
        int idx = tid + i * 256;
        int r = idx >> 2, q = (idx & 3) * 4;
        *(float4*)(x0s + r * 16 + q) =
            *(const float4*)(X + (size_t)(rowBase + r) * K_DIM + q);
        *(float4*)(w0s + r * 16 + q) =
            *(const float4*)(Wt + (size_t)(colBase + r) * K_DIM + q);
    }
    __syncthreads();

    const float TAU32 = (float)TAU_D;
    float wv[4][16];
    float bv[4];
    #pragma unroll
    for (int n = 0; n < 4; ++n) {
        int c = wc * 64 + n * 16 + lr;
        #pragma unroll
        for (int q = 0; q < 4; ++q)
            *(f32x4*)&wv[n][q * 4] = *(const f32x4*)(w0s + c * 16 + q * 4);
        bv[n] = bias[colBase + c];
    }

    #pragma unroll
    for (int m = 0; m < 4; ++m) {
        #pragma unroll
        for (int j = 0; j < 4; ++j) {
            const int r = wr * 64 + m * 16 + lq * 4 + j;
            float xv[16];
            #pragma unroll
            for (int q = 0; q < 4; ++q)
                *(f32x4*)&xv[q * 4] = *(const f32x4*)(x0s + r * 16 + q * 4);
            const size_t orow = (size_t)(rowBase + r) * N_DIM + colBase;
            #pragma unroll
            for (int n = 0; n < 4; ++n) {
                float y1 = 0.f, s2 = 0.f;
                #pragma unroll
                for (int k = 0; k < 16; ++k) {
                    float xk = xv[k];
                    float wk = wv[n][k];
                    float xx = xk * xk;
                    float ww = wk * wk;
                    y1 = fmaf(xk, wk, y1);
                    s2 = fmaf(xx, ww, s2);
                }
                float t = fabsf(y1) / sqrtf(s2 * 0.0625f);
                float v = (t < TAU32) ? 0.0f : (acc[m][n][j] + bv[n]);
                out[orow + wc * 64 + n * 16 + lr] = v;
            }
        }
    }
}

extern "C" void kernel_launch(void* const* d_in, const int* in_sizes, int n_in,
                              void* d_out, int out_size, void* d_ws, size_t ws_size,
                              hipStream_t stream) {
    const float* x    = (const float*)d_in[0];
    const float* W    = (const float*)d_in[1];
    const float* bias = (const float*)d_in[2];
    float* out = (float*)d_out;

    const size_t needA = (size_t)M_DIM * K_DIM * 2;   // 64 MB
    const size_t needB = (size_t)N_DIM * K_DIM * 2;   // 32 MB

    if (ws_size >= needA + needB) {
        unsigned short* xb = (unsigned short*)d_ws;
        unsigned short* wb = (unsigned short*)((char*)d_ws + needA);
        cvt_f32_to_bf16<<<2048, 256, 0, stream>>>(
            (const float4*)x, (uint2*)xb, (M_DIM * K_DIM) / 4);
        cvt_f32_to_bf16<<<2048, 256, 0, stream>>>(
            (const float4*)W, (uint2*)wb, (N_DIM * K_DIM) / 4);
        dim3 grid((M_DIM / 256) * (N_DIM / 128));     // 1024 blocks, 1-D
        gemm_masked8<<<grid, 512, 0, stream>>>(xb, wb, x, W, bias, out);
    } else {
        dim3 grid(N_DIM / 128, M_DIM / 128);
        gemm_masked_fb<<<grid, 256, 0, stream>>>(x, W, bias, out);
    }
}

// Round 18
// 371.650 us; speedup vs baseline: 1.1168x; 1.1168x over previous
//
#include <hip/hip_runtime.h>
#include <cstdint>
#include <cstddef>

#define TAU_D 2.053748910631823
#define M_DIM 8192
#define N_DIM 4096
#define K_DIM 4096
#define NT32  (K_DIM / 32)     // 128 K-steps of BK=32

typedef float f32x4  __attribute__((ext_vector_type(4)));
typedef short bf16x8 __attribute__((ext_vector_type(8)));

typedef __attribute__((address_space(1))) void gvoid_t;
typedef __attribute__((address_space(3))) void lvoid_t;

__device__ __forceinline__ void gload_lds16(const void* g, void* l) {
    __builtin_amdgcn_global_load_lds((const gvoid_t*)g, (lvoid_t*)l, 16, 0, 0);
}

__device__ __forceinline__ unsigned int pack2bf(float lo, float hi) {
    unsigned int ul = __float_as_uint(lo);
    unsigned int uh = __float_as_uint(hi);
    ul = (ul + 0x7FFFu + ((ul >> 16) & 1u)) >> 16;
    uh = (uh + 0x7FFFu + ((uh >> 16) & 1u)) >> 16;
    return ul | (uh << 16);
}

// fp32 -> bf16 (RNE), vectorized: 16B in / 8B out per thread per iter.
__global__ void cvt_f32_to_bf16(const float4* __restrict__ in,
                                uint2* __restrict__ out, int n4) {
    int i = blockIdx.x * blockDim.x + threadIdx.x;
    const int stride = gridDim.x * blockDim.x;
    for (; i < n4; i += stride) {
        float4 a = in[i];
        uint2 o;
        o.x = pack2bf(a.x, a.y);
        o.y = pack2bf(a.z, a.w);
        out[i] = o;
    }
}

// Raw barrier + compiler-only memory fence.
#define BAR() do { __builtin_amdgcn_s_barrier(); \
                   asm volatile("" ::: "memory"); } while (0)

// ============================================================================
// 2-BLOCKS/CU CROSS-BLOCK MULTIPLEXING -- r17 with the launch_bounds FIXED.
// r17's __launch_bounds__(512,4) was honored as CUDA min-BLOCKS-per-CU ->
// 32-waves/CU target -> 64-reg unified cap -> accumulator spill (VGPR=64,
// WRITE +207MB scratch). Session evidence: every (512,2) kernel got the
// 128-reg cap. Fix: (512,2) = 16 waves/CU cap = 128 regs (arch ~60 + 64
// acc) -- no spill; LDS 72KB/block still gives 2 blocks/CU.
//   256x128 tile, 8 waves (4M x 2N), per-wave 64x64 -> acc = 64 regs,
//   BK=32: aF[4]+bF[4] = 32 regs.
// Per K-step span (ONE barrier): [reads A4+B4 | stage(T+2)->buf[(T+2)%3] |
// 16 MFMA (setprio) | vmcnt(3) | BAR]. Co-resident block fills the bubbles.
// Ledger: prologue stages K0,K1, vmcnt(3) -> K0 landed. Span T: outstanding
// at vmcnt = [T+1's 3][T+2's 3]; vmcnt(3) forces T+1 (read next span), 3 fly.
// Tail: T=NT-2 vmcnt(0); T=NT-1 none. WAR: buf[(T+2)%3] last read span T-1,
// one barrier + >=400cy gload-write latency apart (validated r7/r14-r17).
// Swizzle (r7-verified, BK=32): phys 16B-slot = (logical + (row>>1)) & 3;
// staging pre-rotates the GLOBAL source column; LDS dest linear.
// XCD map: 1024 blocks; per XCD per round an 8x8 tile cluster (bijective).
// Epilogue: bit-exact fp32 sgemm-replica mask (verified r3-r17), n-paired
// line-complete stores.
// ============================================================================
__global__ __launch_bounds__(512, 2) void gemm_masked8(
    const unsigned short* __restrict__ Ab,   // x bf16 [M][K]
    const unsigned short* __restrict__ Bb,   // W bf16 [N][K]
    const float* __restrict__ X,             // x fp32 (mask)
    const float* __restrict__ Wt,            // W fp32 (mask)
    const float* __restrict__ bias,
    float* __restrict__ out)
{
    __shared__ __align__(16) char lds[73728];   // 3 x (A 16KB + B 8KB)

    const int tid  = threadIdx.x;
    const int wave = tid >> 6;
    const int lane = tid & 63;
    const int lr = lane & 15;
    const int lq = lane >> 4;
    const int wm = wave >> 1;    // 0..3 : 64-row slice
    const int wn = wave & 1;     // 0..1 : 64-col slice

    // XCD cluster map: 1024 blocks, 2 blocks/CU -> 512 concurrent (round 0).
    // xcd = flat&7; per XCD per round: 8 tile-rows x 8 tile-cols. Bijective.
    const int flat = blockIdx.x;
    const int xcd  = flat & 7;
    const int s    = flat >> 3;            // 0..127
    const int rnd  = s >> 6;               // 0..1
    const int jj   = s & 63;               // 0..63
    const int trow = rnd * 16 + ((xcd >> 2) << 3) + (jj >> 3);   // 0..31
    const int tcol = ((xcd & 3) << 3) + (jj & 7);                // 0..31
    const int rowBase = trow * 256;
    const int colBase = tcol * 128;

    f32x4 acc[4][4];
    #pragma unroll
    for (int i = 0; i < 4; ++i)
        #pragma unroll
        for (int n = 0; n < 4; ++n)
            acc[i][n] = (f32x4){0.f, 0.f, 0.f, 0.f};

    // ---- staging (r7-verified swizzle): linear LDS dest; src col rotated --
    // A pass i (i=0,1): row = i*128 + (tid>>2), phys slot = tid&3.
    // B single pass:    row = tid>>2 (0..127),  phys slot = tid&3.
    // logical slot = ((tid&3) - ((tid>>3)&3)) & 3  (phys = (log+(row>>1))&3).
    const int srow = tid >> 2;                                   // 0..127
    const int slog = ((tid & 3) - ((tid >> 3) & 3)) & 3;
    const unsigned short* aSrc =
        Ab + (size_t)(rowBase + srow) * K_DIM + slog * 8;
    const unsigned short* bSrc =
        Bb + (size_t)(colBase + srow) * K_DIM + slog * 8;

    auto stageK = [&](int kst, unsigned bo) {   // 3 gloads: A x2 + B x1
        #pragma unroll
        for (int i = 0; i < 2; ++i)
            gload_lds16(aSrc + (size_t)i * 128 * K_DIM + kst * 32,
                        lds + bo + i * 8192 + wave * 1024);
        gload_lds16(bSrc + kst * 32, lds + bo + 16384 + wave * 1024);
    };

    // ---- ds_read offsets: byte = row*64 + ((lq + (lr>>1)) & 3)*16 ----
    const unsigned rot  = (unsigned)((lq + (lr >> 1)) & 3) * 16;
    const unsigned offA = (unsigned)(wm * 64 + lr) * 64 + rot;          // +m*1024
    const unsigned offB = 16384u + (unsigned)(wn * 64 + lr) * 64 + rot; // +n*1024

    // ---- prologue: stage K0,K1; vmcnt(3) (K0 landed, K1 flying); BAR ----
    stageK(0, 0);
    stageK(1, 24576);
    asm volatile("s_waitcnt vmcnt(3)" ::: "memory");
    BAR();

    unsigned b0 = 0, b1 = 24576, b2 = 49152;   // read T / T+1 / stage T+2

    for (int T = 0; T < NT32; ++T) {
        const char* L = lds + b0;

        bf16x8 aF[4], bF[4];
        #pragma unroll
        for (int m = 0; m < 4; ++m)
            aF[m] = *(const bf16x8*)(L + offA + m * 1024);
        #pragma unroll
        for (int n = 0; n < 4; ++n)
            bF[n] = *(const bf16x8*)(L + offB + n * 1024);
        if (T + 2 < NT32) stageK(T + 2, b2);

        __builtin_amdgcn_s_setprio(1);
        #pragma unroll
        for (int m = 0; m < 4; ++m)
            #pragma unroll
            for (int n = 0; n < 4; ++n)
                acc[m][n] = __builtin_amdgcn_mfma_f32_16x16x32_bf16(
                    aF[m], bF[n], acc[m][n], 0, 0, 0);
        __builtin_amdgcn_s_setprio(0);

        if (T + 2 < NT32) {
            asm volatile("s_waitcnt vmcnt(3)" ::: "memory");  // T+1 landed
        } else if (T + 1 < NT32) {
            asm volatile("s_waitcnt vmcnt(0)" ::: "memory");  // tail drain
        }
        BAR();

        unsigned t = b0; b0 = b1; b1 = b2; b2 = t;
    }

    // ---- epilogue: bit-exact fp32 mask + bias + store (verified r3-r17) ---
    __syncthreads();
    float* x0s = (float*)(lds);            // [256][16] f32, 16KB
    float* w0s = (float*)(lds + 16384);    // [128][16] f32, 8KB
    #pragma unroll
    for (int i = 0; i < 2; ++i) {
        int idx = tid + i * 512;           // 1024 float4 slots
        int r = idx >> 2, qq = (idx & 3) << 2;
        *(f32x4*)(x0s + r * 16 + qq) =
            *(const f32x4*)(X + (size_t)(rowBase + r) * K_DIM + qq);
    }
    {
        int r = tid >> 2, qq = (tid & 3) << 2;   // 512 float4 slots
        *(f32x4*)(w0s + r * 16 + qq) =
            *(const f32x4*)(Wt + (size_t)(colBase + r) * K_DIM + qq);
    }
    __syncthreads();

    const float TAU32 = (float)TAU_D;

    // n in adjacent pairs: both 64B halves of each 128B output line stored
    // back-to-back (write-amplification fix, verified r6-r17).
    #pragma unroll
    for (int np = 0; np < 4; np += 2) {
        float wv[2][16];
        float bv[2];
        #pragma unroll
        for (int e = 0; e < 2; ++e) {
            const int c = wn * 64 + (np + e) * 16 + lr;
            #pragma unroll
            for (int q = 0; q < 4; ++q)
                *(f32x4*)&wv[e][q * 4] = *(const f32x4*)(w0s + c * 16 + q * 4);
            bv[e] = bias[colBase + c];
        }
        #pragma unroll
        for (int mi = 0; mi < 4; ++mi) {
            #pragma unroll
            for (int jr = 0; jr < 4; ++jr) {
                const int rw = wm * 64 + mi * 16 + lq * 4 + jr;
                float xv[16];
                #pragma unroll
                for (int q = 0; q < 4; ++q)
                    *(f32x4*)&xv[q * 4] = *(const f32x4*)(x0s + rw * 16 + q * 4);
                const size_t orow = (size_t)(rowBase + rw) * N_DIM + colBase;
                #pragma unroll
                for (int e = 0; e < 2; ++e) {
                    const int n = np + e;
                    // Replicate BLAS sgemm: single-acc fma chain, k ascending.
                    float y1 = 0.f, s2 = 0.f;
                    #pragma unroll
                    for (int k = 0; k < 16; ++k) {
                        float xk = xv[k], wk = wv[e][k];
                        float xx = xk * xk, ww = wk * wk;
                        y1 = fmaf(xk, wk, y1);
                        s2 = fmaf(xx, ww, s2);
                    }
                    float t = fabsf(y1) / sqrtf(s2 * 0.0625f);
                    float v = (t < TAU32) ? 0.0f : (acc[mi][n][jr] + bv[e]);
                    out[orow + wn * 64 + n * 16 + lr] = v;
                }
            }
        }
    }
}

// ============================================================================
// Fallback (no workspace): round-3 verified 128x128 kernel, reg-staged cvt.
// ============================================================================
__global__ __launch_bounds__(256, 2) void gemm_masked_fb(
    const float* __restrict__ X, const float* __restrict__ Wt,
    const float* __restrict__ bias, float* __restrict__ out)
{
    __shared__ __align__(16) unsigned short As[128 * 32];
    __shared__ __align__(16) unsigned short Bs[128 * 32];

    const int tid  = threadIdx.x;
    const int wave = tid >> 6;
    const int lane = tid & 63;
    const int rowBase = blockIdx.y * 128;
    const int colBase = blockIdx.x * 128;
    const int wr = wave >> 1;
    const int wc = wave & 1;
    const int lr = lane & 15;
    const int lq = lane >> 4;

    f32x4 acc[4][4];
    #pragma unroll
    for (int m = 0; m < 4; ++m)
        #pragma unroll
        for (int n = 0; n < 4; ++n)
            acc[m][n] = (f32x4){0.f, 0.f, 0.f, 0.f};

    const int srow = tid >> 2;
    const int scol = (tid & 3) * 8;
    const float* afp = X  + (size_t)(rowBase + srow) * K_DIM + scol;
    const float* bfp = Wt + (size_t)(colBase + srow) * K_DIM + scol;

    for (int kt = 0; kt < K_DIM; kt += 32) {
        #pragma unroll
        for (int issue = 0; issue < 2; ++issue) {
            const float* sa = afp + (size_t)issue * 64 * K_DIM;
            const float* sb = bfp + (size_t)issue * 64 * K_DIM;
            float4 a0 = *(const float4*)(sa);
            float4 a1 = *(const float4*)(sa + 4);
            float4 b0 = *(const float4*)(sb);
            float4 b1 = *(const float4*)(sb + 4);
            uint4 pa, pb;
            pa.x = pack2bf(a0.x, a0.y); pa.y = pack2bf(a0.z, a0.w);
            pa.z = pack2bf(a1.x, a1.y); pa.w = pack2bf(a1.z, a1.w);
            pb.x = pack2bf(b0.x, b0.y); pb.y = pack2bf(b0.z, b0.w);
            pb.z = pack2bf(b1.x, b1.y); pb.w = pack2bf(b1.z, b1.w);
            *(uint4*)((char*)As + issue * 4096 + tid * 16) = pa;
            *(uint4*)((char*)Bs + issue * 4096 + tid * 16) = pb;
        }
        afp += 32; bfp += 32;
        __syncthreads();

        bf16x8 af[4], bq[4];
        #pragma unroll
        for (int m = 0; m < 4; ++m)
            af[m] = *(const bf16x8*)(As + (wr * 64 + m * 16 + lr) * 32 + lq * 8);
        #pragma unroll
        for (int n = 0; n < 4; ++n)
            bq[n] = *(const bf16x8*)(Bs + (wc * 64 + n * 16 + lr) * 32 + lq * 8);
        #pragma unroll
        for (int m = 0; m < 4; ++m)
            #pragma unroll
            for (int n = 0; n < 4; ++n)
                acc[m][n] = __builtin_amdgcn_mfma_f32_16x16x32_bf16(
                    af[m], bq[n], acc[m][n], 0, 0, 0);
        __syncthreads();
    }

    float* x0s = (float*)As;
    float* w0s = (float*)Bs;
    #pragma unroll
    for (int i = 0; i < 2; ++i) {
        int idx = tid + i * 256;
        int r = idx >> 2, q = (idx & 3) * 4;
        *(float4*)(x0s + r * 16 + q) =
            *(const float4*)(X + (size_t)(rowBase + r) * K_DIM + q);
        *(float4*)(w0s + r * 16 + q) =
            *(const float4*)(Wt + (size_t)(colBase + r) * K_DIM + q);
    }
    __syncthreads();

    const float TAU32 = (float)TAU_D;
    float wv[4][16];
    float bv[4];
    #pragma unroll
    for (int n = 0; n < 4; ++n) {
        int c = wc * 64 + n * 16 + lr;
        #pragma unroll
        for (int q = 0; q < 4; ++q)
            *(f32x4*)&wv[n][q * 4] = *(const f32x4*)(w0s + c * 16 + q * 4);
        bv[n] = bias[colBase + c];
    }

    #pragma unroll
    for (int m = 0; m < 4; ++m) {
        #pragma unroll
        for (int j = 0; j < 4; ++j) {
            const int r = wr * 64 + m * 16 + lq * 4 + j;
            float xv[16];
            #pragma unroll
            for (int q = 0; q < 4; ++q)
                *(f32x4*)&xv[q * 4] = *(const f32x4*)(x0s + r * 16 + q * 4);
            const size_t orow = (size_t)(rowBase + r) * N_DIM + colBase;
            #pragma unroll
            for (int n = 0; n < 4; ++n) {
                float y1 = 0.f, s2 = 0.f;
                #pragma unroll
                for (int k = 0; k < 16; ++k) {
                    float xk = xv[k];
                    float wk = wv[n][k];
                    float xx = xk * xk;
                    float ww = wk * wk;
                    y1 = fmaf(xk, wk, y1);
                    s2 = fmaf(xx, ww, s2);
                }
                float t = fabsf(y1) / sqrtf(s2 * 0.0625f);
                float v = (t < TAU32) ? 0.0f : (acc[m][n][j] + bv[n]);
                out[orow + wc * 64 + n * 16 + lr] = v;
            }
        }
    }
}

extern "C" void kernel_launch(void* const* d_in, const int* in_sizes, int n_in,
                              void* d_out, int out_size, void* d_ws, size_t ws_size,
                              hipStream_t stream) {
    const float* x    = (const float*)d_in[0];
    const float* W    = (const float*)d_in[1];
    const float* bias = (const float*)d_in[2];
    float* out = (float*)d_out;

    const size_t needA = (size_t)M_DIM * K_DIM * 2;   // 64 MB
    const size_t needB = (size_t)N_DIM * K_DIM * 2;   // 32 MB

    if (ws_size >= needA + needB) {
        unsigned short* xb = (unsigned short*)d_ws;
        unsigned short* wb = (unsigned short*)((char*)d_ws + needA);
        cvt_f32_to_bf16<<<2048, 256, 0, stream>>>(
            (const float4*)x, (uint2*)xb, (M_DIM * K_DIM) / 4);
        cvt_f32_to_bf16<<<2048, 256, 0, stream>>>(
            (const float4*)W, (uint2*)wb, (N_DIM * K_DIM) / 4);
        dim3 grid((M_DIM / 256) * (N_DIM / 128));     // 1024 blocks, 1-D
        gemm_masked8<<<grid, 512, 0, stream>>>(xb, wb, x, W, bias, out);
    } else {
        dim3 grid(N_DIM / 128, M_DIM / 128);
        gemm_masked_fb<<<grid, 256, 0, stream>>>(x, W, bias, out);
    }
}

// Round 19
// 305.422 us; speedup vs baseline: 1.3590x; 1.2168x over previous
//
#include <hip/hip_runtime.h>
#include <cstdint>
#include <cstddef>

#define TAU_D 2.053748910631823
#define M_DIM 8192
#define N_DIM 4096
#define K_DIM 4096
#define NIT   32               // iterations; each covers 2 K-steps of BK=64

typedef float f32x4  __attribute__((ext_vector_type(4)));
typedef short bf16x8 __attribute__((ext_vector_type(8)));

typedef __attribute__((address_space(1))) void gvoid_t;
typedef __attribute__((address_space(3))) void lvoid_t;

__device__ __forceinline__ void gload_lds16(const void* g, void* l) {
    __builtin_amdgcn_global_load_lds((const gvoid_t*)g, (lvoid_t*)l, 16, 0, 0);
}

__device__ __forceinline__ unsigned int pack2bf(float lo, float hi) {
    unsigned int ul = __float_as_uint(lo);
    unsigned int uh = __float_as_uint(hi);
    ul = (ul + 0x7FFFu + ((ul >> 16) & 1u)) >> 16;
    uh = (uh + 0x7FFFu + ((uh >> 16) & 1u)) >> 16;
    return ul | (uh << 16);
}

// fp32 -> bf16 (RNE). SINGLE dispatch converts x then W (both contiguous
// reads; outputs land at xb / wb respectively). 16B in / 8B out per iter.
__global__ void cvt_both_to_bf16(const float4* __restrict__ x4,  int nx4,
                                 const float4* __restrict__ w4,  int nw4,
                                 uint2* __restrict__ xb, uint2* __restrict__ wb) {
    const int stride = gridDim.x * blockDim.x;
    int i = blockIdx.x * blockDim.x + threadIdx.x;
    for (int t = i; t < nx4; t += stride) {
        float4 a = x4[t];
        uint2 o; o.x = pack2bf(a.x, a.y); o.y = pack2bf(a.z, a.w);
        xb[t] = o;
    }
    for (int t = i; t < nw4; t += stride) {
        float4 a = w4[t];
        uint2 o; o.x = pack2bf(a.x, a.y); o.y = pack2bf(a.z, a.w);
        wb[t] = o;
    }
}

// Raw barrier + compiler-only memory fence.
#define BAR() do { __builtin_amdgcn_s_barrier(); \
                   asm volatile("" ::: "memory"); } while (0)

// ============================================================================
// r14 EXACTLY (session best: GEMM 272us, 1007 TF, MfmaUtil 47%).
// Phase = [reads(p); stage(p); (vmcnt); BAR; MFMA(p)] -- reads issue BEFORE
// the barrier (latency hides under barrier wait), ONE barrier per phase.
// WAR safety BY CONSTRUCTION: every region's restage phase is >=2 phases
// after its last read:  R1A read ph7(prev) -> staged ph1-2 ; R0B read ph2 ->
// staged ph4-5 ; R0A read ph3 -> staged ph6-7 ; R1B read ph6 -> staged ph8.
// vmcnt BEFORE the barrier (publication): vmcnt(2)@ph4 forces A(kb),B(kb);
// vmcnt(4)@ph8 forces A,B(ka+2). Tail: ph4 vmcnt(0). Prologue: vmcnt(4)+BAR.
// Geometry/swizzle/XCD map/epilogue verified r3-r18 (absmax 2.0).
// 12 schedule/occupancy variants (r7-r18) all land <= this one; cross-block
// multiplexing falsified (r17/r18); this is the plain-HIP plateau here.
// ============================================================================
__global__ __launch_bounds__(512, 2) void gemm_masked8(
    const unsigned short* __restrict__ Ab,   // x bf16 [M][K]
    const unsigned short* __restrict__ Bb,   // W bf16 [N][K]
    const float* __restrict__ X,             // x fp32 (mask)
    const float* __restrict__ Wt,            // W fp32 (mask)
    const float* __restrict__ bias,
    float* __restrict__ out)
{
    __shared__ __align__(16) char lds[131072];   // R0A|R0B|R1A|R1B x 32KB

    const int tid  = threadIdx.x;
    const int wave = tid >> 6;
    const int lane = tid & 63;
    const int lr = lane & 15;
    const int lq = lane >> 4;
    const int wm = wave >> 2;    // 0..1 : row half (128 rows)
    const int wn = wave & 3;     // 0..3 : 64-col slice

    // Concurrency-aware XCD cluster map (verified r6).
    const int flat = blockIdx.x;
    const int xcd  = flat & 7;
    const int s    = flat >> 3;            // 0..63
    const int rnd  = s >> 5;               // 0..1
    const int jj   = s & 31;               // 0..31
    const int trow = rnd * 16 + ((xcd >> 2) << 3) + (jj >> 2);   // 0..31
    const int tcol = ((xcd & 3) << 2) + (jj & 3);                // 0..15
    const int rowBase = trow * 256;
    const int colBase = tcol * 256;

    f32x4 acc[8][4];
    #pragma unroll
    for (int i = 0; i < 8; ++i)
        #pragma unroll
        for (int n = 0; n < 4; ++n)
            acc[i][n] = (f32x4){0.f, 0.f, 0.f, 0.f};

    // ---- staging (r6-verified): linear LDS dest; global col pre-swizzled --
    const int srow  = tid >> 3;                       // 0..63
    const int sslot = (tid & 7) ^ (srow & 7);
    const unsigned short* aSrc =
        Ab + (size_t)(rowBase + srow) * K_DIM + sslot * 8;
    const unsigned short* bSrc =
        Bb + (size_t)(colBase + srow) * K_DIM + sslot * 8;

    const unsigned R0A = 0, R0B = 32768, R1A = 65536, R1B = 98304;

    auto stageHalfA = [&](int kst, unsigned reg, int h) {
        #pragma unroll
        for (int i = 2 * h; i < 2 * h + 2; ++i)
            gload_lds16(aSrc + (size_t)i * 64 * K_DIM + kst * 64,
                        lds + reg + i * 8192 + wave * 1024);
    };
    auto stageHalfB = [&](int kst, unsigned reg, int h) {
        #pragma unroll
        for (int i = 2 * h; i < 2 * h + 2; ++i)
            gload_lds16(bSrc + (size_t)i * 64 * K_DIM + kst * 64,
                        lds + reg + i * 8192 + wave * 1024);
    };

    // ---- ds_read offsets (r6-verified swizzle) ----
    const unsigned kk0 = (unsigned)((lq) ^ (lr & 7)) * 16;
    const unsigned kk1 = (unsigned)((4 + lq) ^ (lr & 7)) * 16;
    const unsigned rowA = (unsigned)(wm * 128 + lr) * 128;   // + m*2048
    const unsigned rowB = (unsigned)(wn * 64 + lr) * 128;    // + nf*2048

    // ---- prologue: A(0),B(0)->R0; B(1)->R1B; vmcnt(4); publication BAR ----
    stageHalfA(0, R0A, 0); stageHalfA(0, R0A, 1);
    stageHalfB(0, R0B, 0); stageHalfB(0, R0B, 1);
    stageHalfB(1, R1B, 0); stageHalfB(1, R1B, 1);
    asm volatile("s_waitcnt vmcnt(4)" ::: "memory");   // A0,B0 landed
    BAR();

    bf16x8 aF[4][2];     // A quadrant (q0 ph1-2 / q1 ph3-4; reloaded per half)
    bf16x8 bF0[2][2];    // B nq0 (lives ph1..ph4 of its K-step)
    bf16x8 bF1[2][2];    // B nq1 (lives ph2..ph3)

    #define MFMA_QUAD(ACC_M, ACC_N, BREG)                                      \
        do {                                                                   \
            __builtin_amdgcn_s_setprio(1);                                     \
            _Pragma("unroll")                                                  \
            for (int m = 0; m < 4; ++m)                                        \
                _Pragma("unroll")                                              \
                for (int n = 0; n < 2; ++n)                                    \
                    _Pragma("unroll")                                          \
                    for (int ks = 0; ks < 2; ++ks)                             \
                        acc[(ACC_M) + m][(ACC_N) + n] =                        \
                            __builtin_amdgcn_mfma_f32_16x16x32_bf16(           \
                                aF[m][ks], BREG[n][ks],                        \
                                acc[(ACC_M) + m][(ACC_N) + n], 0, 0, 0);       \
            __builtin_amdgcn_s_setprio(0);                                     \
        } while (0)

    for (int j = 0; j < NIT; ++j) {
        const int ka = 2 * j;
        const int kb = 2 * j + 1;
        const bool stg = (j + 1 < NIT);

        // ---- ph1: reads A q0 + B nq0 (R0); stage A(kb)h0->R1A; BAR; MFMA --
        #pragma unroll
        for (int m = 0; m < 4; ++m) {
            aF[m][0] = *(const bf16x8*)(lds + R0A + rowA + m * 2048 + kk0);
            aF[m][1] = *(const bf16x8*)(lds + R0A + rowA + m * 2048 + kk1);
        }
        #pragma unroll
        for (int n = 0; n < 2; ++n) {
            bF0[n][0] = *(const bf16x8*)(lds + R0B + rowB + n * 2048 + kk0);
            bF0[n][1] = *(const bf16x8*)(lds + R0B + rowB + n * 2048 + kk1);
        }
        stageHalfA(kb, R1A, 0);
        BAR();
        MFMA_QUAD(0, 0, bF0);

        // ---- ph2: reads B nq1 (R0); stage A(kb)h1->R1A; BAR; MFMA ----
        #pragma unroll
        for (int n = 0; n < 2; ++n) {
            bF1[n][0] = *(const bf16x8*)(lds + R0B + rowB + (2 + n) * 2048 + kk0);
            bF1[n][1] = *(const bf16x8*)(lds + R0B + rowB + (2 + n) * 2048 + kk1);
        }
        stageHalfA(kb, R1A, 1);
        BAR();
        MFMA_QUAD(0, 2, bF1);

        // ---- ph3: reads A q1 (R0); BAR; MFMA ----
        #pragma unroll
        for (int m = 0; m < 4; ++m) {
            aF[m][0] = *(const bf16x8*)(lds + R0A + rowA + (4 + m) * 2048 + kk0);
            aF[m][1] = *(const bf16x8*)(lds + R0A + rowA + (4 + m) * 2048 + kk1);
        }
        BAR();
        MFMA_QUAD(4, 2, bF1);

        // ---- ph4: stage B(ka+2)h0->R0B; vmcnt; BAR; MFMA ----
        if (stg) {
            stageHalfB(ka + 2, R0B, 0);
            asm volatile("s_waitcnt vmcnt(2)" ::: "memory");  // A(kb),B(kb) landed
        } else {
            asm volatile("s_waitcnt vmcnt(0)" ::: "memory");  // tail drain
        }
        BAR();
        MFMA_QUAD(4, 0, bF0);

        // ---- ph5: reads A q0 + B nq0 (R1); stage B(ka+2)h1->R0B; BAR; MFMA
        #pragma unroll
        for (int m = 0; m < 4; ++m) {
            aF[m][0] = *(const bf16x8*)(lds + R1A + rowA + m * 2048 + kk0);
            aF[m][1] = *(const bf16x8*)(lds + R1A + rowA + m * 2048 + kk1);
        }
        #pragma unroll
        for (int n = 0; n < 2; ++n) {
            bF0[n][0] = *(const bf16x8*)(lds + R1B + rowB + n * 2048 + kk0);
            bF0[n][1] = *(const bf16x8*)(lds + R1B + rowB + n * 2048 + kk1);
        }
        if (stg) stageHalfB(ka + 2, R0B, 1);
        BAR();
        MFMA_QUAD(0, 0, bF0);

        // ---- ph6: reads B nq1 (R1); stage A(ka+2)h0->R0A; BAR; MFMA ----
        #pragma unroll
        for (int n = 0; n < 2; ++n) {
            bF1[n][0] = *(const bf16x8*)(lds + R1B + rowB + (2 + n) * 2048 + kk0);
            bF1[n][1] = *(const bf16x8*)(lds + R1B + rowB + (2 + n) * 2048 + kk1);
        }
        if (stg) stageHalfA(ka + 2, R0A, 0);
        BAR();
        MFMA_QUAD(0, 2, bF1);

        // ---- ph7: reads A q1 (R1); stage A(ka+2)h1->R0A; BAR; MFMA ----
        #pragma unroll
        for (int m = 0; m < 4; ++m) {
            aF[m][0] = *(const bf16x8*)(lds + R1A + rowA + (4 + m) * 2048 + kk0);
            aF[m][1] = *(const bf16x8*)(lds + R1A + rowA + (4 + m) * 2048 + kk1);
        }
        if (stg) stageHalfA(ka + 2, R0A, 1);
        BAR();
        MFMA_QUAD(4, 2, bF1);

        // ---- ph8: stage B(kb+2)x4->R1B; vmcnt(4); BAR; MFMA ----
        if (stg) {
            stageHalfB(kb + 2, R1B, 0);
            stageHalfB(kb + 2, R1B, 1);
            asm volatile("s_waitcnt vmcnt(4)" ::: "memory");  // A,B(ka+2) landed
        }
        BAR();
        MFMA_QUAD(4, 0, bF0);
    }

    // ---- epilogue: bit-exact fp32 mask + bias + store (verified r3-r18) ---
    __syncthreads();
    float* x0s = (float*)(lds);            // [256][16] f32, 16KB
    float* w0s = (float*)(lds + 16384);    // [256][16] f32
    #pragma unroll
    for (int i = 0; i < 2; ++i) {
        int idx = tid + i * 512;           // 1024 float4 slots
        int r = idx >> 2, qq = (idx & 3) << 2;
        *(f32x4*)(x0s + r * 16 + qq) =
            *(const f32x4*)(X + (size_t)(rowBase + r) * K_DIM + qq);
        *(f32x4*)(w0s + r * 16 + qq) =
            *(const f32x4*)(Wt + (size_t)(colBase + r) * K_DIM + qq);
    }
    __syncthreads();

    const float TAU32 = (float)TAU_D;

    // n in adjacent pairs: both 64B halves of each 128B output line stored
    // back-to-back (write-amplification fix, verified r6-r18).
    #pragma unroll
    for (int np = 0; np < 4; np += 2) {
        float wv[2][16];
        float bv[2];
        #pragma unroll
        for (int e = 0; e < 2; ++e) {
            const int c = wn * 64 + (np + e) * 16 + lr;
            #pragma unroll
            for (int q = 0; q < 4; ++q)
                *(f32x4*)&wv[e][q * 4] = *(const f32x4*)(w0s + c * 16 + q * 4);
            bv[e] = bias[colBase + c];
        }
        #pragma unroll
        for (int mi = 0; mi < 8; ++mi) {
            #pragma unroll
            for (int jr = 0; jr < 4; ++jr) {
                const int rw = wm * 128 + mi * 16 + lq * 4 + jr;
                float xv[16];
                #pragma unroll
                for (int q = 0; q < 4; ++q)
                    *(f32x4*)&xv[q * 4] = *(const f32x4*)(x0s + rw * 16 + q * 4);
                const size_t orow = (size_t)(rowBase + rw) * N_DIM + colBase;
                #pragma unroll
                for (int e = 0; e < 2; ++e) {
                    const int n = np + e;
                    // Replicate BLAS sgemm: single-acc fma chain, k ascending.
                    float y1 = 0.f, s2 = 0.f;
                    #pragma unroll
                    for (int k = 0; k < 16; ++k) {
                        float xk = xv[k], wk = wv[e][k];
                        float xx = xk * xk, ww = wk * wk;
                        y1 = fmaf(xk, wk, y1);
                        s2 = fmaf(xx, ww, s2);
                    }
                    float t = fabsf(y1) / sqrtf(s2 * 0.0625f);
                    float v = (t < TAU32) ? 0.0f : (acc[mi][n][jr] + bv[e]);
                    out[orow + wn * 64 + n * 16 + lr] = v;
                }
            }
        }
    }
}

// ============================================================================
// Fallback (no workspace): round-3 verified 128x128 kernel, reg-staged cvt.
// ============================================================================
__global__ __launch_bounds__(256, 2) void gemm_masked_fb(
    const float* __restrict__ X, const float* __restrict__ Wt,
    const float* __restrict__ bias, float* __restrict__ out)
{
    __shared__ __align__(16) unsigned short As[128 * 32];
    __shared__ __align__(16) unsigned short Bs[128 * 32];

    const int tid  = threadIdx.x;
    const int wave = tid >> 6;
    const int lane = tid & 63;
    const int rowBase = blockIdx.y * 128;
    const int colBase = blockIdx.x * 128;
    const int wr = wave >> 1;
    const int wc = wave & 1;
    const int lr = lane & 15;
    const int lq = lane >> 4;

    f32x4 acc[4][4];
    #pragma unroll
    for (int m = 0; m < 4; ++m)
        #pragma unroll
        for (int n = 0; n < 4; ++n)
            acc[m][n] = (f32x4){0.f, 0.f, 0.f, 0.f};

    const int srow = tid >> 2;
    const int scol = (tid & 3) * 8;
    const float* afp = X  + (size_t)(rowBase + srow) * K_DIM + scol;
    const float* bfp = Wt + (size_t)(colBase + srow) * K_DIM + scol;

    for (int kt = 0; kt < K_DIM; kt += 32) {
        #pragma unroll
        for (int issue = 0; issue < 2; ++issue) {
            const float* sa = afp + (size_t)issue * 64 * K_DIM;
            const float* sb = bfp + (size_t)issue * 64 * K_DIM;
            float4 a0 = *(const float4*)(sa);
            float4 a1 = *(const float4*)(sa + 4);
            float4 b0 = *(const float4*)(sb);
            float4 b1 = *(const float4*)(sb + 4);
            uint4 pa, pb;
            pa.x = pack2bf(a0.x, a0.y); pa.y = pack2bf(a0.z, a0.w);
            pa.z = pack2bf(a1.x, a1.y); pa.w = pack2bf(a1.z, a1.w);
            pb.x = pack2bf(b0.x, b0.y); pb.y = pack2bf(b0.z, b0.w);
            pb.z = pack2bf(b1.x, b1.y); pb.w = pack2bf(b1.z, b1.w);
            *(uint4*)((char*)As + issue * 4096 + tid * 16) = pa;
            *(uint4*)((char*)Bs + issue * 4096 + tid * 16) = pb;
        }
        afp += 32; bfp += 32;
        __syncthreads();

        bf16x8 af[4], bq[4];
        #pragma unroll
        for (int m = 0; m < 4; ++m)
            af[m] = *(const bf16x8*)(As + (wr * 64 + m * 16 + lr) * 32 + lq * 8);
        #pragma unroll
        for (int n = 0; n < 4; ++n)
            bq[n] = *(const bf16x8*)(Bs + (wc * 64 + n * 16 + lr) * 32 + lq * 8);
        #pragma unroll
        for (int m = 0; m < 4; ++m)
            #pragma unroll
            for (int n = 0; n < 4; ++n)
                acc[m][n] = __builtin_amdgcn_mfma_f32_16x16x32_bf16(
                    af[m], bq[n], acc[m][n], 0, 0, 0);
        __syncthreads();
    }

    float* x0s = (float*)As;
    float* w0s = (float*)Bs;
    #pragma unroll
    for (int i = 0; i < 2; ++i) {
        int idx = tid + i * 256;
        int r = idx >> 2, q = (idx & 3) * 4;
        *(float4*)(x0s + r * 16 + q) =
            *(const float4*)(X + (size_t)(rowBase + r) * K_DIM + q);
        *(float4*)(w0s + r * 16 + q) =
            *(const float4*)(Wt + (size_t)(colBase + r) * K_DIM + q);
    }
    __syncthreads();

    const float TAU32 = (float)TAU_D;
    float wv[4][16];
    float bv[4];
    #pragma unroll
    for (int n = 0; n < 4; ++n) {
        int c = wc * 64 + n * 16 + lr;
        #pragma unroll
        for (int q = 0; q < 4; ++q)
            *(f32x4*)&wv[n][q * 4] = *(const f32x4*)(w0s + c * 16 + q * 4);
        bv[n] = bias[colBase + c];
    }

    #pragma unroll
    for (int m = 0; m < 4; ++m) {
        #pragma unroll
        for (int j = 0; j < 4; ++j) {
            const int r = wr * 64 + m * 16 + lq * 4 + j;
            float xv[16];
            #pragma unroll
            for (int q = 0; q < 4; ++q)
                *(f32x4*)&xv[q * 4] = *(const f32x4*)(x0s + r * 16 + q * 4);
            const size_t orow = (size_t)(rowBase + r) * N_DIM + colBase;
            #pragma unroll
            for (int n = 0; n < 4; ++n) {
                float y1 = 0.f, s2 = 0.f;
                #pragma unroll
                for (int k = 0; k < 16; ++k) {
                    float xk = xv[k];
                    float wk = wv[n][k];
                    float xx = xk * xk;
                    float ww = wk * wk;
                    y1 = fmaf(xk, wk, y1);
                    s2 = fmaf(xx, ww, s2);
                }
                float t = fabsf(y1) / sqrtf(s2 * 0.0625f);
                float v = (t < TAU32) ? 0.0f : (acc[m][n][j] + bv[n]);
                out[orow + wc * 64 + n * 16 + lr] = v;
            }
        }
    }
}

extern "C" void kernel_launch(void* const* d_in, const int* in_sizes, int n_in,
                              void* d_out, int out_size, void* d_ws, size_t ws_size,
                              hipStream_t stream) {
    const float* x    = (const float*)d_in[0];
    const float* W    = (const float*)d_in[1];
    const float* bias = (const float*)d_in[2];
    float* out = (float*)d_out;

    const size_t needA = (size_t)M_DIM * K_DIM * 2;   // 64 MB
    const size_t needB = (size_t)N_DIM * K_DIM * 2;   // 32 MB

    if (ws_size >= needA + needB) {
        unsigned short* xb = (unsigned short*)d_ws;
        unsigned short* wb = (unsigned short*)((char*)d_ws + needA);
        cvt_both_to_bf16<<<2048, 256, 0, stream>>>(
            (const float4*)x, (M_DIM * K_DIM) / 4,
            (const float4*)W, (N_DIM * K_DIM) / 4,
            (uint2*)xb, (uint2*)wb);
        dim3 grid((M_DIM / 256) * (N_DIM / 256));     // 512 blocks, 1-D
        gemm_masked8<<<grid, 512, 0, stream>>>(xb, wb, x, W, bias, out);
    } else {
        dim3 grid(N_DIM / 128, M_DIM / 128);
        gemm_masked_fb<<<grid, 256, 0, stream>>>(x, W, bias, out);
    }
}